// Round 6
// baseline (333.153 us; speedup 1.0000x reference)
//
#include <hip/hip_runtime.h>
#include <hip/hip_bf16.h>

typedef __bf16 bf16_t;
typedef __bf16 bf16x8 __attribute__((ext_vector_type(8)));
typedef float  f32x4  __attribute__((ext_vector_type(4)));

#define S_LEN 4096
#define NH    8
#define DH    64
#define DE    512

// ---------------------------------------------------------------------------
// GEMM tile params (both projection GEMMs)
// ---------------------------------------------------------------------------
#define BM 128
#define BN 128
#define BK 32
#define LDP 40

static __device__ __forceinline__ void stage16_f32(bf16_t* dst, const float* src) {
    const float4 v0 = *reinterpret_cast<const float4*>(src + 0);
    const float4 v1 = *reinterpret_cast<const float4*>(src + 4);
    const float4 v2 = *reinterpret_cast<const float4*>(src + 8);
    const float4 v3 = *reinterpret_cast<const float4*>(src + 12);
    bf16x8 lo, hi;
    lo[0]=(bf16_t)v0.x; lo[1]=(bf16_t)v0.y; lo[2]=(bf16_t)v0.z; lo[3]=(bf16_t)v0.w;
    lo[4]=(bf16_t)v1.x; lo[5]=(bf16_t)v1.y; lo[6]=(bf16_t)v1.z; lo[7]=(bf16_t)v1.w;
    hi[0]=(bf16_t)v2.x; hi[1]=(bf16_t)v2.y; hi[2]=(bf16_t)v2.z; hi[3]=(bf16_t)v2.w;
    hi[4]=(bf16_t)v3.x; hi[5]=(bf16_t)v3.y; hi[6]=(bf16_t)v3.z; hi[7]=(bf16_t)v3.w;
    *reinterpret_cast<bf16x8*>(dst + 0) = lo;
    *reinterpret_cast<bf16x8*>(dst + 8) = hi;
}

// ---------------------------------------------------------------------------
// Kernel 1: qkv = x @ w_in^T + b_in ; scatter to Q [h][s][64], K [h][s][64],
//           V^T [h][64][s]   (all bf16)
// ---------------------------------------------------------------------------
__global__ __launch_bounds__(256) void qkv_gemm(
    const float* __restrict__ X,
    const float* __restrict__ Win,
    const float* __restrict__ bin,
    bf16_t* __restrict__ qw,
    bf16_t* __restrict__ kw,
    bf16_t* __restrict__ vtw)
{
    __shared__ bf16_t As[BM * LDP];
    __shared__ bf16_t Bs[BN * LDP];

    const int tid  = threadIdx.x;
    const int lane = tid & 63;
    const int w    = tid >> 6;
    const int wr   = w >> 1, wc = w & 1;
    const int row0 = blockIdx.y * BM;
    const int col0 = blockIdx.x * BN;

    const int fr = lane & 15;
    const int fo = (lane >> 4) * 8;
    const int cr = (lane >> 4) * 4;

    const int sr = tid >> 1;
    const int sc = (tid & 1) * 16;

    f32x4 acc[4][4] = {};

    for (int k0 = 0; k0 < DE; k0 += BK) {
        stage16_f32(As + sr * LDP + sc, X   + (row0 + sr) * DE + k0 + sc);
        stage16_f32(Bs + sr * LDP + sc, Win + (col0 + sr) * DE + k0 + sc);
        __syncthreads();

        bf16x8 af[4], bf[4];
        #pragma unroll
        for (int m = 0; m < 4; ++m)
            af[m] = *reinterpret_cast<const bf16x8*>(As + (wr * 64 + m * 16 + fr) * LDP + fo);
        #pragma unroll
        for (int n = 0; n < 4; ++n)
            bf[n] = *reinterpret_cast<const bf16x8*>(Bs + (wc * 64 + n * 16 + fr) * LDP + fo);
        #pragma unroll
        for (int m = 0; m < 4; ++m)
            #pragma unroll
            for (int n = 0; n < 4; ++n)
                acc[m][n] = __builtin_amdgcn_mfma_f32_16x16x32_bf16(af[m], bf[n], acc[m][n], 0, 0, 0);
        __syncthreads();
    }

    #pragma unroll
    for (int m = 0; m < 4; ++m) {
        #pragma unroll
        for (int n = 0; n < 4; ++n) {
            const int col = col0 + wc * 64 + n * 16 + fr;
            const float b = bin[col];
            const int part = col >> 9;
            const int cd   = col & 511;
            const int h    = cd >> 6;
            const int d    = cd & 63;
            #pragma unroll
            for (int r = 0; r < 4; ++r) {
                const int row = row0 + wr * 64 + m * 16 + cr + r;
                const float v = acc[m][n][r] + b;
                const bf16_t bv = (bf16_t)v;
                if (part == 0)      qw [(h * S_LEN + row) * DH + d] = bv;
                else if (part == 1) kw [(h * S_LEN + row) * DH + d] = bv;
                else                vtw[(h * DH + d) * S_LEN + row] = bv;
            }
        }
    }
}

// ---------------------------------------------------------------------------
// Kernel 2: attention, softmax over HEADS axis.
// Block = QT queries x KS-way key split, 8 waves = 8 heads, lockstep 64-key
// phases. Double-buffered e-LDS -> 2 barriers/tile. Cross-head normalize
// rewrites e -> w in place.
//
// r5 post-mortem: QT=64 (QF=4) still spilled ~170 MB/dispatch (WRITE_SIZE
// 187 MB vs 16 MB real) and 128 KB LDS pinned 1 block/CU = 2 waves/SIMD
// (occupancy 23%) -> latency-bound at MfmaUtil 8%. Fix: QT=32 (QF=2)
// halves both LDS (64 KB -> 2 blocks/CU = 4 waves/SIMD) and register
// demand (~80-100 live, fits 128 with no spill); grid 512, all blocks
// co-resident. __launch_bounds__(512,4) pins the 128-reg budget that
// guarantees 16 waves/CU.
// ---------------------------------------------------------------------------
template<int QT, int KS>
__global__ __launch_bounds__(512, 4) void attn_kernel(
    const bf16_t* __restrict__ qw,    // [h][s][64]
    const bf16_t* __restrict__ kw,    // [h][s][64]
    const bf16_t* __restrict__ vtw,   // [h][64][s]
    const int*    __restrict__ causal_p,
    bf16_t* __restrict__ part)        // [KS][s][512] partial outputs
{
    constexpr int QF = QT / 16;
    constexpr int NT = (S_LEN / KS) / 64;
    constexpr int KSH = (KS == 4) ? 2 : (KS == 2 ? 1 : 0);

    // [2 buffers][head][q][64 keys], 16B-block XOR swizzle b' = b ^ (q&7)
    __shared__ bf16_t e_lds[2][NH][QT][64];

    const int tid  = threadIdx.x;
    const int lane = tid & 63;
    const int h    = tid >> 6;
    const int kc   = blockIdx.x & (KS - 1);       // key chunk -> XCD-aligned
    const int q0   = (blockIdx.x >> KSH) * QT;
    const int kbase = kc * (S_LEN / KS);
    const int causal = causal_p[0];

    const int fr  = lane & 15;
    const int fog = lane >> 4;
    const int fo  = fog * 8;
    const int cr  = fog * 4;

    // Q fragments (own head): QF row-frags x 2 k-halves (persistent)
    bf16x8 aq[QF][2];
    #pragma unroll
    for (int qf = 0; qf < QF; ++qf) {
        const bf16_t* qb = qw + ((size_t)(h * S_LEN) + q0 + qf * 16 + fr) * DH;
        aq[qf][0] = *reinterpret_cast<const bf16x8*>(qb + fo);
        aq[qf][1] = *reinterpret_cast<const bf16x8*>(qb + 32 + fo);
    }

    f32x4 o[QF][4] = {};   // accumulators (AGPR side of unified file)

    for (int t = 0; t < NT; ++t) {
        const int kg = kbase + t * 64;
        bf16_t* wbuf = &e_lds[t & 1][h][0][0];

        // ---- QK^T + exp -> write e(t) into buf[t&1] ----
        #pragma unroll
        for (int kf = 0; kf < 4; ++kf) {
            const bf16_t* kb = kw + ((size_t)(h * S_LEN) + kg + kf * 16 + fr) * DH;
            const bf16x8 b0 = *reinterpret_cast<const bf16x8*>(kb + fo);
            const bf16x8 b1 = *reinterpret_cast<const bf16x8*>(kb + 32 + fo);
            #pragma unroll
            for (int qf = 0; qf < QF; ++qf) {
                f32x4 z = {};
                z = __builtin_amdgcn_mfma_f32_16x16x32_bf16(aq[qf][0], b0, z, 0, 0, 0);
                z = __builtin_amdgcn_mfma_f32_16x16x32_bf16(aq[qf][1], b1, z, 0, 0, 0);
                #pragma unroll
                for (int r = 0; r < 4; ++r) {
                    float val = __expf(z[r] * 0.125f);
                    if (causal) {
                        if (kg + kf * 16 + fr > q0 + qf * 16 + cr + r) val = 0.f;
                    }
                    const int q = qf * 16 + cr + r;
                    const int k = kf * 16 + fr;
                    const int bp = (k >> 3) ^ (q & 7);
                    wbuf[q * 64 + bp * 8 + (k & 7)] = (bf16_t)val;
                }
            }
        }

        __syncthreads();   // all e(t) writes visible

        // ---- cross-head normalize in place: e -> w = e / sum_h e ----
        if (tid < QT * 8) {
            const int q  = tid >> 3;
            const int bb = tid & 7;
            const int bp = bb ^ (q & 7);
            bf16_t* base = &e_lds[t & 1][0][0][0] + q * 64 + bp * 8;
            bf16x8 eh[NH];
            float den[8] = {};
            #pragma unroll
            for (int hh = 0; hh < NH; ++hh) {
                eh[hh] = *reinterpret_cast<const bf16x8*>(base + hh * (QT * 64));
                #pragma unroll
                for (int j = 0; j < 8; ++j) den[j] += (float)eh[hh][j];
            }
            float rd[8];
            #pragma unroll
            for (int j = 0; j < 8; ++j)
                rd[j] = (den[j] > 0.f) ? __builtin_amdgcn_rcpf(den[j]) : 0.f;
            #pragma unroll
            for (int hh = 0; hh < NH; ++hh) {
                bf16x8 wv;
                #pragma unroll
                for (int j = 0; j < 8; ++j) wv[j] = (bf16_t)((float)eh[hh][j] * rd[j]);
                *reinterpret_cast<bf16x8*>(base + hh * (QT * 64)) = wv;
            }
        }
        __syncthreads();   // w(t) ready

        // ---- PV(t): o += w(t) @ V(t); pa/vv loaded just-in-time ----
        #pragma unroll
        for (int c = 0; c < 2; ++c) {
            bf16x8 pa[QF];
            #pragma unroll
            for (int qf = 0; qf < QF; ++qf) {
                const int q  = qf * 16 + fr;
                const int bp = (4 * c + fog) ^ (q & 7);
                pa[qf] = *reinterpret_cast<const bf16x8*>(wbuf + q * 64 + bp * 8);
            }
            #pragma unroll
            for (int n = 0; n < 4; ++n) {
                const bf16x8 vvn = *reinterpret_cast<const bf16x8*>(
                    vtw + ((size_t)(h * DH + n * 16 + fr)) * S_LEN + kg + c * 32 + fo);
                #pragma unroll
                for (int qf = 0; qf < QF; ++qf)
                    o[qf][n] = __builtin_amdgcn_mfma_f32_16x16x32_bf16(pa[qf], vvn, o[qf][n], 0, 0, 0);
            }
        }
        // next tile writes the other buffer; no extra barrier needed
    }

    // write partial output tile [QT][512] bf16
    bf16_t* pp = part + (size_t)kc * (S_LEN * DE);
    #pragma unroll
    for (int qf = 0; qf < QF; ++qf)
        #pragma unroll
        for (int n = 0; n < 4; ++n)
            #pragma unroll
            for (int r = 0; r < 4; ++r)
                pp[(size_t)(q0 + qf * 16 + cr + r) * DE + h * 64 + n * 16 + fr] =
                    (bf16_t)o[qf][n][r];
}

// ---------------------------------------------------------------------------
// Kernel 3: out = (sum_kc part_kc) @ w_out^T + b_out   (f32 output)
// ---------------------------------------------------------------------------
template<int KS>
__global__ __launch_bounds__(256) void out_gemm(
    const bf16_t* __restrict__ part,   // [KS][4096][512] bf16
    const float*  __restrict__ Wout,
    const float*  __restrict__ bout,
    float* __restrict__ out)
{
    __shared__ bf16_t As[BM * LDP];
    __shared__ bf16_t Bs[BN * LDP];

    const int tid  = threadIdx.x;
    const int lane = tid & 63;
    const int w    = tid >> 6;
    const int wr   = w >> 1, wc = w & 1;
    const int row0 = blockIdx.y * BM;
    const int col0 = blockIdx.x * BN;

    const int fr = lane & 15;
    const int fo = (lane >> 4) * 8;
    const int cr = (lane >> 4) * 4;

    const int sr = tid >> 1;
    const int sc = (tid & 1) * 16;

    f32x4 acc[4][4] = {};

    for (int k0 = 0; k0 < DE; k0 += BK) {
        // A staging: sum KS partials (bf16 -> f32 add -> bf16)
        {
            const size_t off = (size_t)(row0 + sr) * DE + k0 + sc;
            #pragma unroll
            for (int v = 0; v < 2; ++v) {
                bf16x8 a = *reinterpret_cast<const bf16x8*>(part + off + v * 8);
                #pragma unroll
                for (int p = 1; p < KS; ++p) {
                    bf16x8 b = *reinterpret_cast<const bf16x8*>(
                        part + (size_t)p * (S_LEN * DE) + off + v * 8);
                    #pragma unroll
                    for (int j = 0; j < 8; ++j)
                        a[j] = (bf16_t)((float)a[j] + (float)b[j]);
                }
                *reinterpret_cast<bf16x8*>(As + sr * LDP + sc + v * 8) = a;
            }
        }
        stage16_f32(Bs + sr * LDP + sc, Wout + (col0 + sr) * DE + k0 + sc);
        __syncthreads();

        bf16x8 af[4], bf[4];
        #pragma unroll
        for (int m = 0; m < 4; ++m)
            af[m] = *reinterpret_cast<const bf16x8*>(As + (wr * 64 + m * 16 + fr) * LDP + fo);
        #pragma unroll
        for (int n = 0; n < 4; ++n)
            bf[n] = *reinterpret_cast<const bf16x8*>(Bs + (wc * 64 + n * 16 + fr) * LDP + fo);
        #pragma unroll
        for (int m = 0; m < 4; ++m)
            #pragma unroll
            for (int n = 0; n < 4; ++n)
                acc[m][n] = __builtin_amdgcn_mfma_f32_16x16x32_bf16(af[m], bf[n], acc[m][n], 0, 0, 0);
        __syncthreads();
    }

    #pragma unroll
    for (int m = 0; m < 4; ++m) {
        #pragma unroll
        for (int n = 0; n < 4; ++n) {
            const int col = col0 + wc * 64 + n * 16 + fr;
            const float b = bout[col];
            #pragma unroll
            for (int r = 0; r < 4; ++r) {
                const int row = row0 + wr * 64 + m * 16 + cr + r;
                out[row * DE + col] = acc[m][n][r] + b;
            }
        }
    }
}

// ---------------------------------------------------------------------------
// Launch: pick key-split factor by available workspace.
//   needs (3 + KS) * 4 MiB of d_ws.
// ---------------------------------------------------------------------------
extern "C" void kernel_launch(void* const* d_in, const int* in_sizes, int n_in,
                              void* d_out, int out_size, void* d_ws, size_t ws_size,
                              hipStream_t stream) {
    const float* x     = (const float*)d_in[0];
    const float* w_in  = (const float*)d_in[1];
    const float* b_in  = (const float*)d_in[2];
    const float* w_out = (const float*)d_in[3];
    const float* b_out = (const float*)d_in[4];
    const int*   causal = (const int*)d_in[5];
    float* out = (float*)d_out;

    const size_t segE = (size_t)NH * S_LEN * DH;      // 2M bf16 elems = 4 MiB
    bf16_t* qw   = (bf16_t*)d_ws;
    bf16_t* kw   = qw  + segE;
    bf16_t* vtw  = kw  + segE;
    bf16_t* part = vtw + segE;

    dim3 g1(3 * DE / BN, S_LEN / BM);   // (12, 32)
    qkv_gemm<<<g1, 256, 0, stream>>>(x, w_in, b_in, qw, kw, vtw);

    dim3 g3(DE / BN, S_LEN / BM);       // (4, 32)

    const size_t segB = segE * sizeof(bf16_t);        // 4 MiB
    if (ws_size >= 7 * segB) {
        // QT=32, KS=4: grid = 4 * (4096/32) = 512 blocks, 2 blocks/CU
        attn_kernel<32, 4><<<512, 512, 0, stream>>>(qw, kw, vtw, causal, part);
        out_gemm<4><<<g3, 256, 0, stream>>>(part, w_out, b_out, out);
    } else if (ws_size >= 5 * segB) {
        attn_kernel<32, 2><<<256, 512, 0, stream>>>(qw, kw, vtw, causal, part);
        out_gemm<2><<<g3, 256, 0, stream>>>(part, w_out, b_out, out);
    } else {
        attn_kernel<16, 1><<<256, 512, 0, stream>>>(qw, kw, vtw, causal, part);
        out_gemm<1><<<g3, 256, 0, stream>>>(part, w_out, b_out, out);
    }
}

// Round 7
// 193.150 us; speedup vs baseline: 1.7248x; 1.7248x over previous
//
#include <hip/hip_runtime.h>
#include <hip/hip_bf16.h>

typedef __bf16 bf16_t;
typedef __bf16 bf16x8 __attribute__((ext_vector_type(8)));
typedef __bf16 bf16x4 __attribute__((ext_vector_type(4)));
typedef float  f32x4  __attribute__((ext_vector_type(4)));

#define S_LEN 4096
#define NH    8
#define DH    64
#define DE    512

// ---------------------------------------------------------------------------
// GEMM tile params (both projection GEMMs)
// ---------------------------------------------------------------------------
#define BM 128
#define BN 128
#define BK 32
#define LDP 40

static __device__ __forceinline__ void stage16_f32(bf16_t* dst, const float* src) {
    const float4 v0 = *reinterpret_cast<const float4*>(src + 0);
    const float4 v1 = *reinterpret_cast<const float4*>(src + 4);
    const float4 v2 = *reinterpret_cast<const float4*>(src + 8);
    const float4 v3 = *reinterpret_cast<const float4*>(src + 12);
    bf16x8 lo, hi;
    lo[0]=(bf16_t)v0.x; lo[1]=(bf16_t)v0.y; lo[2]=(bf16_t)v0.z; lo[3]=(bf16_t)v0.w;
    lo[4]=(bf16_t)v1.x; lo[5]=(bf16_t)v1.y; lo[6]=(bf16_t)v1.z; lo[7]=(bf16_t)v1.w;
    hi[0]=(bf16_t)v2.x; hi[1]=(bf16_t)v2.y; hi[2]=(bf16_t)v2.z; hi[3]=(bf16_t)v2.w;
    hi[4]=(bf16_t)v3.x; hi[5]=(bf16_t)v3.y; hi[6]=(bf16_t)v3.z; hi[7]=(bf16_t)v3.w;
    *reinterpret_cast<bf16x8*>(dst + 0) = lo;
    *reinterpret_cast<bf16x8*>(dst + 8) = hi;
}

// ---------------------------------------------------------------------------
// Kernel 1: qkv = x @ w_in^T + b_in ; scatter to Q [h][s][64], K [h][s][64],
//           V^T [h][64][s]   (all bf16)
// ---------------------------------------------------------------------------
__global__ __launch_bounds__(256) void qkv_gemm(
    const float* __restrict__ X,
    const float* __restrict__ Win,
    const float* __restrict__ bin,
    bf16_t* __restrict__ qw,
    bf16_t* __restrict__ kw,
    bf16_t* __restrict__ vtw)
{
    __shared__ bf16_t As[BM * LDP];
    __shared__ bf16_t Bs[BN * LDP];

    const int tid  = threadIdx.x;
    const int lane = tid & 63;
    const int w    = tid >> 6;
    const int wr   = w >> 1, wc = w & 1;
    const int row0 = blockIdx.y * BM;
    const int col0 = blockIdx.x * BN;

    const int fr = lane & 15;
    const int fo = (lane >> 4) * 8;
    const int cr = (lane >> 4) * 4;

    const int sr = tid >> 1;
    const int sc = (tid & 1) * 16;

    f32x4 acc[4][4] = {};

    for (int k0 = 0; k0 < DE; k0 += BK) {
        stage16_f32(As + sr * LDP + sc, X   + (row0 + sr) * DE + k0 + sc);
        stage16_f32(Bs + sr * LDP + sc, Win + (col0 + sr) * DE + k0 + sc);
        __syncthreads();

        bf16x8 af[4], bf[4];
        #pragma unroll
        for (int m = 0; m < 4; ++m)
            af[m] = *reinterpret_cast<const bf16x8*>(As + (wr * 64 + m * 16 + fr) * LDP + fo);
        #pragma unroll
        for (int n = 0; n < 4; ++n)
            bf[n] = *reinterpret_cast<const bf16x8*>(Bs + (wc * 64 + n * 16 + fr) * LDP + fo);
        #pragma unroll
        for (int m = 0; m < 4; ++m)
            #pragma unroll
            for (int n = 0; n < 4; ++n)
                acc[m][n] = __builtin_amdgcn_mfma_f32_16x16x32_bf16(af[m], bf[n], acc[m][n], 0, 0, 0);
        __syncthreads();
    }

    #pragma unroll
    for (int m = 0; m < 4; ++m) {
        #pragma unroll
        for (int n = 0; n < 4; ++n) {
            const int col = col0 + wc * 64 + n * 16 + fr;
            const float b = bin[col];
            const int part = col >> 9;
            const int cd   = col & 511;
            const int h    = cd >> 6;
            const int d    = cd & 63;
            #pragma unroll
            for (int r = 0; r < 4; ++r) {
                const int row = row0 + wr * 64 + m * 16 + cr + r;
                const float v = acc[m][n][r] + b;
                const bf16_t bv = (bf16_t)v;
                if (part == 0)      qw [(h * S_LEN + row) * DH + d] = bv;
                else if (part == 1) kw [(h * S_LEN + row) * DH + d] = bv;
                else                vtw[(h * DH + d) * S_LEN + row] = bv;
            }
        }
    }
}

// ---------------------------------------------------------------------------
// Kernel 2: attention, softmax over HEADS axis.
// Block = QT queries x KS-way key split, 8 waves = 8 heads, lockstep 64-key
// phases. Double-buffered e-LDS -> 2 barriers/tile.
//
// r6 post-mortem: __launch_bounds__(512,4) caps ARCH VGPRs at 64 (other
// half of the 128 budget is AGPR). The kf-unrolled QK^T (32 regs of hoisted
// K-frags) and eh[8] in normalize (32 regs) blew past 64 -> 259 MB spill
// stores, L2 thrash, FETCH 350 MB. Fix: keep the geometry (QT=32, 64 KB
// LDS, 2 blocks/CU, 45% occupancy was achieved) but cut arch demand:
//   - normalize is a 2-pass stream (den only, no eh[8] array)
//   - #pragma unroll 1 on kf / c loops stops operand hoisting
// Peak arch live ~50 < 64, AGPR = o (32) < 64 -> zero spill.
// ---------------------------------------------------------------------------
template<int QT, int KS>
__global__ __launch_bounds__(512, 4) void attn_kernel(
    const bf16_t* __restrict__ qw,    // [h][s][64]
    const bf16_t* __restrict__ kw,    // [h][s][64]
    const bf16_t* __restrict__ vtw,   // [h][64][s]
    const int*    __restrict__ causal_p,
    bf16_t* __restrict__ part)        // [KS][s][512] partial outputs
{
    constexpr int QF = QT / 16;
    constexpr int NT = (S_LEN / KS) / 64;
    constexpr int KSH = (KS == 4) ? 2 : (KS == 2 ? 1 : 0);

    // [2 buffers][head][q][64 keys], 16B-block XOR swizzle b' = b ^ (q&7)
    __shared__ bf16_t e_lds[2][NH][QT][64];

    const int tid  = threadIdx.x;
    const int lane = tid & 63;
    const int h    = tid >> 6;
    const int kc   = blockIdx.x & (KS - 1);       // key chunk -> XCD-aligned
    const int q0   = (blockIdx.x >> KSH) * QT;
    const int kbase = kc * (S_LEN / KS);
    const int causal = causal_p[0];

    const int fr  = lane & 15;
    const int fog = lane >> 4;
    const int fo  = fog * 8;
    const int cr  = fog * 4;

    // Q fragments (own head): QF row-frags x 2 k-halves (persistent, 16 regs)
    bf16x8 aq[QF][2];
    #pragma unroll
    for (int qf = 0; qf < QF; ++qf) {
        const bf16_t* qb = qw + ((size_t)(h * S_LEN) + q0 + qf * 16 + fr) * DH;
        aq[qf][0] = *reinterpret_cast<const bf16x8*>(qb + fo);
        aq[qf][1] = *reinterpret_cast<const bf16x8*>(qb + 32 + fo);
    }

    f32x4 o[QF][4] = {};   // accumulators (AGPR side of unified file)

    for (int t = 0; t < NT; ++t) {
        const int kg = kbase + t * 64;
        bf16_t* wbuf = &e_lds[t & 1][h][0][0];

        // ---- QK^T + exp -> write e(t) into buf[t&1] ----
        // unroll 1: keep only one kf's K-fragments (8 regs) live at a time
        #pragma unroll 1
        for (int kf = 0; kf < 4; ++kf) {
            const bf16_t* kb = kw + ((size_t)(h * S_LEN) + kg + kf * 16 + fr) * DH;
            const bf16x8 b0 = *reinterpret_cast<const bf16x8*>(kb + fo);
            const bf16x8 b1 = *reinterpret_cast<const bf16x8*>(kb + 32 + fo);
            #pragma unroll
            for (int qf = 0; qf < QF; ++qf) {
                f32x4 z = {};
                z = __builtin_amdgcn_mfma_f32_16x16x32_bf16(aq[qf][0], b0, z, 0, 0, 0);
                z = __builtin_amdgcn_mfma_f32_16x16x32_bf16(aq[qf][1], b1, z, 0, 0, 0);
                #pragma unroll
                for (int r = 0; r < 4; ++r) {
                    float val = __expf(z[r] * 0.125f);
                    if (causal) {
                        if (kg + kf * 16 + fr > q0 + qf * 16 + cr + r) val = 0.f;
                    }
                    const int q = qf * 16 + cr + r;
                    const int k = kf * 16 + fr;
                    const int bp = (k >> 3) ^ (q & 7);
                    wbuf[q * 64 + bp * 8 + (k & 7)] = (bf16_t)val;
                }
            }
        }

        __syncthreads();   // all e(t) writes visible

        // ---- cross-head normalize in place, 2-pass (no eh[] array) ----
        // 512 threads x 4 (q,k) pairs: q = tid>>4, 8B sub-block hb = tid&15
        if (tid < QT * 16) {
            const int q  = tid >> 4;
            const int hb = tid & 15;
            const int bp = (hb >> 1) ^ (q & 7);
            bf16_t* base = &e_lds[t & 1][0][0][0] + q * 64 + bp * 8 + (hb & 1) * 4;

            float den0 = 0.f, den1 = 0.f, den2 = 0.f, den3 = 0.f;
            #pragma unroll
            for (int hh = 0; hh < NH; ++hh) {
                const bf16x4 v = *reinterpret_cast<const bf16x4*>(base + hh * (QT * 64));
                den0 += (float)v[0]; den1 += (float)v[1];
                den2 += (float)v[2]; den3 += (float)v[3];
            }
            const float rd0 = (den0 > 0.f) ? __builtin_amdgcn_rcpf(den0) : 0.f;
            const float rd1 = (den1 > 0.f) ? __builtin_amdgcn_rcpf(den1) : 0.f;
            const float rd2 = (den2 > 0.f) ? __builtin_amdgcn_rcpf(den2) : 0.f;
            const float rd3 = (den3 > 0.f) ? __builtin_amdgcn_rcpf(den3) : 0.f;
            #pragma unroll
            for (int hh = 0; hh < NH; ++hh) {
                bf16_t* p = base + hh * (QT * 64);
                const bf16x4 v = *reinterpret_cast<const bf16x4*>(p);
                bf16x4 wv;
                wv[0] = (bf16_t)((float)v[0] * rd0);
                wv[1] = (bf16_t)((float)v[1] * rd1);
                wv[2] = (bf16_t)((float)v[2] * rd2);
                wv[3] = (bf16_t)((float)v[3] * rd3);
                *reinterpret_cast<bf16x4*>(p) = wv;
            }
        }
        __syncthreads();   // w(t) ready

        // ---- PV(t): o += w(t) @ V(t); pa/vv loaded just-in-time ----
        #pragma unroll 1
        for (int c = 0; c < 2; ++c) {
            bf16x8 pa[QF];
            #pragma unroll
            for (int qf = 0; qf < QF; ++qf) {
                const int q  = qf * 16 + fr;
                const int bp = (4 * c + fog) ^ (q & 7);
                pa[qf] = *reinterpret_cast<const bf16x8*>(wbuf + q * 64 + bp * 8);
            }
            #pragma unroll
            for (int n = 0; n < 4; ++n) {
                const bf16x8 vvn = *reinterpret_cast<const bf16x8*>(
                    vtw + ((size_t)(h * DH + n * 16 + fr)) * S_LEN + kg + c * 32 + fo);
                #pragma unroll
                for (int qf = 0; qf < QF; ++qf)
                    o[qf][n] = __builtin_amdgcn_mfma_f32_16x16x32_bf16(pa[qf], vvn, o[qf][n], 0, 0, 0);
            }
        }
        // next tile writes the other buffer; no extra barrier needed
    }

    // write partial output tile [QT][512] bf16
    bf16_t* pp = part + (size_t)kc * (S_LEN * DE);
    #pragma unroll
    for (int qf = 0; qf < QF; ++qf)
        #pragma unroll
        for (int n = 0; n < 4; ++n)
            #pragma unroll
            for (int r = 0; r < 4; ++r)
                pp[(size_t)(q0 + qf * 16 + cr + r) * DE + h * 64 + n * 16 + fr] =
                    (bf16_t)o[qf][n][r];
}

// ---------------------------------------------------------------------------
// Kernel 3: out = (sum_kc part_kc) @ w_out^T + b_out   (f32 output)
// ---------------------------------------------------------------------------
template<int KS>
__global__ __launch_bounds__(256) void out_gemm(
    const bf16_t* __restrict__ part,   // [KS][4096][512] bf16
    const float*  __restrict__ Wout,
    const float*  __restrict__ bout,
    float* __restrict__ out)
{
    __shared__ bf16_t As[BM * LDP];
    __shared__ bf16_t Bs[BN * LDP];

    const int tid  = threadIdx.x;
    const int lane = tid & 63;
    const int w    = tid >> 6;
    const int wr   = w >> 1, wc = w & 1;
    const int row0 = blockIdx.y * BM;
    const int col0 = blockIdx.x * BN;

    const int fr = lane & 15;
    const int fo = (lane >> 4) * 8;
    const int cr = (lane >> 4) * 4;

    const int sr = tid >> 1;
    const int sc = (tid & 1) * 16;

    f32x4 acc[4][4] = {};

    for (int k0 = 0; k0 < DE; k0 += BK) {
        // A staging: sum KS partials (bf16 -> f32 add -> bf16)
        {
            const size_t off = (size_t)(row0 + sr) * DE + k0 + sc;
            #pragma unroll
            for (int v = 0; v < 2; ++v) {
                bf16x8 a = *reinterpret_cast<const bf16x8*>(part + off + v * 8);
                #pragma unroll
                for (int p = 1; p < KS; ++p) {
                    bf16x8 b = *reinterpret_cast<const bf16x8*>(
                        part + (size_t)p * (S_LEN * DE) + off + v * 8);
                    #pragma unroll
                    for (int j = 0; j < 8; ++j)
                        a[j] = (bf16_t)((float)a[j] + (float)b[j]);
                }
                *reinterpret_cast<bf16x8*>(As + sr * LDP + sc + v * 8) = a;
            }
        }
        stage16_f32(Bs + sr * LDP + sc, Wout + (col0 + sr) * DE + k0 + sc);
        __syncthreads();

        bf16x8 af[4], bf[4];
        #pragma unroll
        for (int m = 0; m < 4; ++m)
            af[m] = *reinterpret_cast<const bf16x8*>(As + (wr * 64 + m * 16 + fr) * LDP + fo);
        #pragma unroll
        for (int n = 0; n < 4; ++n)
            bf[n] = *reinterpret_cast<const bf16x8*>(Bs + (wc * 64 + n * 16 + fr) * LDP + fo);
        #pragma unroll
        for (int m = 0; m < 4; ++m)
            #pragma unroll
            for (int n = 0; n < 4; ++n)
                acc[m][n] = __builtin_amdgcn_mfma_f32_16x16x32_bf16(af[m], bf[n], acc[m][n], 0, 0, 0);
        __syncthreads();
    }

    #pragma unroll
    for (int m = 0; m < 4; ++m) {
        #pragma unroll
        for (int n = 0; n < 4; ++n) {
            const int col = col0 + wc * 64 + n * 16 + fr;
            const float b = bout[col];
            #pragma unroll
            for (int r = 0; r < 4; ++r) {
                const int row = row0 + wr * 64 + m * 16 + cr + r;
                out[row * DE + col] = acc[m][n][r] + b;
            }
        }
    }
}

// ---------------------------------------------------------------------------
// Launch: pick key-split factor by available workspace.
//   needs (3 + KS) * 4 MiB of d_ws.
// ---------------------------------------------------------------------------
extern "C" void kernel_launch(void* const* d_in, const int* in_sizes, int n_in,
                              void* d_out, int out_size, void* d_ws, size_t ws_size,
                              hipStream_t stream) {
    const float* x     = (const float*)d_in[0];
    const float* w_in  = (const float*)d_in[1];
    const float* b_in  = (const float*)d_in[2];
    const float* w_out = (const float*)d_in[3];
    const float* b_out = (const float*)d_in[4];
    const int*   causal = (const int*)d_in[5];
    float* out = (float*)d_out;

    const size_t segE = (size_t)NH * S_LEN * DH;      // 2M bf16 elems = 4 MiB
    bf16_t* qw   = (bf16_t*)d_ws;
    bf16_t* kw   = qw  + segE;
    bf16_t* vtw  = kw  + segE;
    bf16_t* part = vtw + segE;

    dim3 g1(3 * DE / BN, S_LEN / BM);   // (12, 32)
    qkv_gemm<<<g1, 256, 0, stream>>>(x, w_in, b_in, qw, kw, vtw);

    dim3 g3(DE / BN, S_LEN / BM);       // (4, 32)

    const size_t segB = segE * sizeof(bf16_t);        // 4 MiB
    if (ws_size >= 7 * segB) {
        // QT=32, KS=4: grid = 4 * (4096/32) = 512 blocks, 2 blocks/CU
        attn_kernel<32, 4><<<512, 512, 0, stream>>>(qw, kw, vtw, causal, part);
        out_gemm<4><<<g3, 256, 0, stream>>>(part, w_out, b_out, out);
    } else if (ws_size >= 5 * segB) {
        attn_kernel<32, 2><<<256, 512, 0, stream>>>(qw, kw, vtw, causal, part);
        out_gemm<2><<<g3, 256, 0, stream>>>(part, w_out, b_out, out);
    } else {
        attn_kernel<16, 1><<<256, 512, 0, stream>>>(qw, kw, vtw, causal, part);
        out_gemm<1><<<g3, 256, 0, stream>>>(part, w_out, b_out, out);
    }
}